// Round 4
// baseline (612.762 us; speedup 1.0000x reference)
//
#include <hip/hip_runtime.h>

#define H 128          // hidden dim (fixed by problem)
#define CAP 64         // max edges per (rel,dst) bucket

typedef _Float16 f16x8 __attribute__((ext_vector_type(8)));
typedef _Float16 f16x2 __attribute__((ext_vector_type(2)));
typedef float    f32x4 __attribute__((ext_vector_type(4)));

// ---------------- edge bucketing: one pass, reused by both layers ----------------
__global__ __launch_bounds__(256) void hist_fill(const int* __restrict__ src,
    const int* __restrict__ dst, const int* __restrict__ et,
    int* __restrict__ cnt, int* __restrict__ elist, int E, int N)
{
    int e = blockIdx.x * 256 + threadIdx.x;
    if (e >= E) return;
    int s = src[e], d = dst[e], t = et[e];
    int b = t * N + d;
    int pos = atomicAdd(&cnt[b], 1);
    if (pos < CAP) elist[(size_t)b * CAP + pos] = s;
}

// ---------------- weight prep: transpose + fp32->fp16 ----------------
__global__ __launch_bounds__(256) void prep_w(const float* __restrict__ w_in,
    const float* __restrict__ w_root, const float* __restrict__ w_rel,
    _Float16* __restrict__ wInT, _Float16* __restrict__ w3T, int K)
{
    int idx = blockIdx.x * 256 + threadIdx.x;
    int tot1 = K * H;
    if (idx < tot1) {
        int c = idx / K, k = idx - c * K;
        wInT[idx] = (_Float16)w_in[(size_t)k * H + c];
    } else {
        int i2 = idx - tot1;
        if (i2 < 3 * H * H) {
            int m = i2 / (H * H), r2 = i2 - m * (H * H);
            int c = r2 >> 7, k = r2 & 127;
            const float* s = (m == 0) ? w_root : (w_rel + (size_t)(m - 1) * H * H);
            w3T[i2] = (_Float16)s[(size_t)k * H + c];
        }
    }
}

__device__ __forceinline__ f16x8 cvt8(float4 v0, float4 v1) {
    f16x8 t;
    t[0] = (_Float16)v0.x; t[1] = (_Float16)v0.y; t[2] = (_Float16)v0.z; t[3] = (_Float16)v0.w;
    t[4] = (_Float16)v1.x; t[5] = (_Float16)v1.y; t[6] = (_Float16)v1.z; t[7] = (_Float16)v1.w;
    return t;
}

// ---------------- big MFMA GEMM, zero-LDS, 16x128 per wave -----------------------
// C16 = fp16(leakyrelu(A[M,K] @ W + b)). A fp32 row-major; WT fp16 [col][K].
// One wave owns 16 rows x 128 cols: ONE A-fragment feeds 8 MFMAs -> tiny
// footprint -> explicit 2-deep register ping-pong pipelines the HBM stream.
__global__ __launch_bounds__(256, 2) void gemm_big(const float* __restrict__ A,
    const _Float16* __restrict__ WT, const float* __restrict__ bias,
    _Float16* __restrict__ C16, int M, int K)
{
    const int tid = threadIdx.x;
    const int bm  = blockIdx.x * 64;
    const int w   = tid >> 6;
    const int l   = tid & 63;
    const int l15 = l & 15;
    const int q   = l >> 4;

    int arow = bm + w * 16 + l15;
    if (arow >= M) arow = M - 1;                 // clamp loads; stores predicated
    const float* ap = A + (size_t)arow * K + q * 8;
    const _Float16* bp[8];
#pragma unroll
    for (int j = 0; j < 8; j++)
        bp[j] = WT + (size_t)(j * 16 + l15) * K + q * 8;

    f32x4 acc[8];
    const f32x4 z4 = {0.f, 0.f, 0.f, 0.f};
#pragma unroll
    for (int j = 0; j < 8; j++) acc[j] = z4;

    // prefetch chunk 0
    float4 a0 = *(const float4*)(ap);
    float4 a1 = *(const float4*)(ap + 4);
    f16x8 bcur[8], bnxt[8];
#pragma unroll
    for (int j = 0; j < 8; j++) bcur[j] = *(const f16x8*)(bp[j]);

#pragma unroll 2
    for (int k0 = 32; k0 < K; k0 += 32) {
        float4 a2 = *(const float4*)(ap + k0);
        float4 a3 = *(const float4*)(ap + k0 + 4);
#pragma unroll
        for (int j = 0; j < 8; j++) bnxt[j] = *(const f16x8*)(bp[j] + k0);
        f16x8 af = cvt8(a0, a1);
#pragma unroll
        for (int j = 0; j < 8; j++)
            acc[j] = __builtin_amdgcn_mfma_f32_16x16x32_f16(af, bcur[j], acc[j], 0, 0, 0);
        a0 = a2; a1 = a3;
#pragma unroll
        for (int j = 0; j < 8; j++) bcur[j] = bnxt[j];
    }
    {
        f16x8 af = cvt8(a0, a1);
#pragma unroll
        for (int j = 0; j < 8; j++)
            acc[j] = __builtin_amdgcn_mfma_f32_16x16x32_f16(af, bcur[j], acc[j], 0, 0, 0);
    }

    // epilogue: bias + leaky, fp16 store
#pragma unroll
    for (int j = 0; j < 8; j++) {
        int col = j * 16 + l15;
        float bj = bias[col];
#pragma unroll
        for (int rg = 0; rg < 4; rg++) {
            int row = bm + w * 16 + q * 4 + rg;
            if (row < M) {
                float v = acc[j][rg] + bj;
                v = (v >= 0.f) ? v : 0.01f * v;
                C16[(size_t)row * H + col] = (_Float16)v;
            }
        }
    }
}

// ---------------- fused per-layer GEMM, zero-LDS, fp16 x -------------------------
// y = x@w_root + b (fp32 out); h_r = x@w_rel[r] (fp16 out). x read ONCE into
// registers (no cvt: already fp16), reused across the 3 weight matrices.
__global__ __launch_bounds__(256, 2) void gemm3(const _Float16* __restrict__ X16,
    const _Float16* __restrict__ W3, const float* __restrict__ bias,
    float* __restrict__ Y, _Float16* __restrict__ Hh, int M)
{
    const int tid = threadIdx.x;
    const int bm  = blockIdx.x * 64;
    const int w   = tid >> 6;
    const int l   = tid & 63;
    const int l15 = l & 15;
    const int q   = l >> 4;

    int arow = bm + w * 16 + l15;
    if (arow >= M) arow = M - 1;
    const _Float16* xp = X16 + (size_t)arow * H + q * 8;

    f16x8 xf[4];
#pragma unroll
    for (int kk = 0; kk < 4; kk++) xf[kk] = *(const f16x8*)(xp + kk * 32);

    const f32x4 z4 = {0.f, 0.f, 0.f, 0.f};

    for (int m = 0; m < 3; m++) {
        const _Float16* wb = W3 + (size_t)m * H * H + (size_t)l15 * H + q * 8;
        f32x4 acc[8];
#pragma unroll
        for (int j = 0; j < 8; j++) acc[j] = z4;

#pragma unroll
        for (int kk = 0; kk < 4; kk++) {
            f16x8 bf[8];
#pragma unroll
            for (int j = 0; j < 8; j++)
                bf[j] = *(const f16x8*)(wb + (size_t)(j * 16) * H + kk * 32);
#pragma unroll
            for (int j = 0; j < 8; j++)
                acc[j] = __builtin_amdgcn_mfma_f32_16x16x32_f16(xf[kk], bf[j], acc[j], 0, 0, 0);
        }

        if (m == 0) {
#pragma unroll
            for (int j = 0; j < 8; j++) {
                int col = j * 16 + l15;
                float bj = bias[col];
#pragma unroll
                for (int rg = 0; rg < 4; rg++) {
                    int row = bm + w * 16 + q * 4 + rg;
                    if (row < M) Y[(size_t)row * H + col] = acc[j][rg] + bj;
                }
            }
        } else {
            _Float16* hb = Hh + (size_t)(m - 1) * M * H;
#pragma unroll
            for (int j = 0; j < 8; j++) {
                int col = j * 16 + l15;
#pragma unroll
                for (int rg = 0; rg < 4; rg++) {
                    int row = bm + w * 16 + q * 4 + rg;
                    if (row < M) hb[(size_t)row * H + col] = (_Float16)acc[j][rg];
                }
            }
        }
    }
}

// ---------------- mean-aggregate gather --------------------------------------------
// xn[dst] = fp16( y[dst] + sum_r mean(h_r[src]) ).  One wave per dst row.
__global__ __launch_bounds__(256) void gather_mean(const float* __restrict__ y,
    const _Float16* __restrict__ h, const int* __restrict__ elist,
    const int* __restrict__ cnt, _Float16* __restrict__ xn, int N, int R)
{
    int wv = blockIdx.x * 4 + (threadIdx.x >> 6);
    int lane = threadIdx.x & 63;
    if (wv >= N) return;

    float2 acc = *(const float2*)&y[(size_t)wv * H + lane * 2];
    for (int r = 0; r < R; r++) {
        int b = r * N + wv;
        int deg = cnt[b];
        if (deg == 0) continue;
        int len = deg < CAP ? deg : CAP;
        const int* lst = &elist[(size_t)b * CAP];
        const _Float16* hr = h + (size_t)r * N * H;
        float sx = 0.f, sy = 0.f;
        for (int i = 0; i < len; i++) {
            int s = lst[i];
            f16x2 v = *(const f16x2*)&hr[(size_t)s * H + lane * 2];
            sx += (float)v[0]; sy += (float)v[1];
        }
        float inv = 1.0f / (float)deg;
        acc.x += sx * inv; acc.y += sy * inv;
    }
    f16x2 o; o[0] = (_Float16)acc.x; o[1] = (_Float16)acc.y;
    *(f16x2*)&xn[(size_t)wv * H + lane * 2] = o;
}

// ---------------- final projection: out[N,OUT] = X[N,128] @ Wo[128,OUT] + bo ------
__global__ __launch_bounds__(256) void out_gemm(const _Float16* __restrict__ X16,
    const float* __restrict__ Wo, const float* __restrict__ bo,
    float* __restrict__ out, int N, int OUT)
{
    int row = blockIdx.x * 4 + (threadIdx.x >> 6);
    int lane = threadIdx.x & 63;
    if (row >= N) return;
    float a0 = (float)X16[(size_t)row * H + lane];
    float a1 = (float)X16[(size_t)row * H + 64 + lane];
    for (int c = 0; c < OUT; c++) {
        float p = a0 * Wo[lane * OUT + c] + a1 * Wo[(64 + lane) * OUT + c];
        for (int off = 32; off > 0; off >>= 1) p += __shfl_down(p, off);
        if (lane == 0) out[(size_t)row * OUT + c] = p + bo[c];
    }
}

extern "C" void kernel_launch(void* const* d_in, const int* in_sizes, int n_in,
                              void* d_out, int out_size, void* d_ws, size_t ws_size,
                              hipStream_t stream) {
    const float* feature = (const float*)d_in[0];
    const int*   ei      = (const int*)d_in[1];   // [2,E]: src then dst
    const int*   et      = (const int*)d_in[2];   // [E]
    const float* w_in    = (const float*)d_in[3];
    const float* b_in    = (const float*)d_in[4];
    const float* w_rel   = (const float*)d_in[5];
    const float* w_root  = (const float*)d_in[6];
    const float* b_conv  = (const float*)d_in[7];
    const float* w_out   = (const float*)d_in[8];
    const float* b_out   = (const float*)d_in[9];

    const int HH   = in_sizes[4];                 // 128
    const int D_IN = in_sizes[3] / HH;            // 768
    const int N    = in_sizes[0] / D_IN;          // 50000
    const int E    = in_sizes[1] / 2;             // 600000
    const int R    = in_sizes[5] / (HH * HH);     // 2
    const int OUT  = in_sizes[9];                 // 3

    // workspace layout (16B-aligned segments)
    char* base = (char*)d_ws;
    _Float16* wInT = (_Float16*)base;                              // 128*K
    _Float16* w3T  = wInT + (size_t)D_IN * HH;                     // 3*128*128
    _Float16* x0   = w3T + (size_t)3 * HH * HH;                    // N*H fp16
    _Float16* x1   = x0 + (size_t)N * H;                           // N*H fp16
    _Float16* h    = x1 + (size_t)N * H;                           // R*N*H fp16
    float* y       = (float*)(h + (size_t)R * N * H);              // N*H fp32
    int* cnt       = (int*)(y + (size_t)N * H);                    // R*N
    int* elist     = cnt + (size_t)R * N;                          // R*N*CAP

    hipMemsetAsync(cnt, 0, sizeof(int) * (size_t)R * N, stream);
    prep_w<<<(D_IN * HH + 3 * HH * HH + 255) / 256, 256, 0, stream>>>(
        w_in, w_root, w_rel, wInT, w3T, D_IN);
    hist_fill<<<(E + 255) / 256, 256, 0, stream>>>(ei, ei + E, et, cnt, elist, E, N);

    const int gblocks = (N + 63) / 64;
    // x0 = fp16(leakyrelu(feature @ w_in + b_in))
    gemm_big<<<gblocks, 256, 0, stream>>>(feature, wInT, b_in, x0, N, D_IN);

    _Float16* xc = x0;
    _Float16* xo = x1;
    for (int layer = 0; layer < 2; layer++) {
        gemm3<<<gblocks, 256, 0, stream>>>(xc, w3T, b_conv, y, h, N);
        gather_mean<<<(N + 3) / 4, 256, 0, stream>>>(y, h, elist, cnt, xo, N, R);
        _Float16* t = xc; xc = xo; xo = t;
    }

    out_gemm<<<(N + 3) / 4, 256, 0, stream>>>(xc, w_out, b_out, (float*)d_out, N, OUT);
}